// Round 1
// baseline (580.837 us; speedup 1.0000x reference)
//
#include <hip/hip_runtime.h>

// limiter per reference: idx1 & idx2 is provably always False
// (a*b<=0 and a*b>0 are disjoint), so w = min(|a+b|/2, 2*min(|a|,|b|)).
__device__ __forceinline__ float limiter_f(float a, float b) {
    float x1 = fabsf(a + b) * 0.5f;
    float x2 = 2.0f * fminf(fabsf(a), fabsf(b));
    return fminf(x1, x2);
}

__device__ __forceinline__ float h_func(float V, float dVdt) {
    const float VT = -55.0f;
    const float INV_S_SQRT2 = 0.23570226039551584f;  // 1/(SIGMA*sqrt(2)), SIGMA=3
    float dV = fmaxf(VT - V, -1.0f);
    float T  = dV * INV_S_SQRT2;
    float T2 = T * T;
    // A = exp(0.0061 - 1.12 T - 0.257 T^2 - 0.072 T^3 - 0.0117 T^4)
    float poly = 0.0061f - 1.12f * T - 0.257f * T2 - 0.072f * T2 * T - 0.0117f * T2 * T2;
    float A = expf(poly);
    float dT = fminf(-INV_S_SQRT2 * dVdt, 0.0f);
    float F  = 0.7978845608028654f * expf(-T2) / (1.00000001f + erff(T));
    float B  = -14.142135623730951f * dT * F;        // -sqrt(2)*dT*F*TAU_M
    return fmaxf((A + B) * 0.1f, 0.0f);              // /TAU_M
}

__global__ __launch_bounds__(256) void neuron_kernel(
    const float* __restrict__ z, const float* __restrict__ S,
    const float* __restrict__ V, const float* __restrict__ dVdt,
    float* __restrict__ out, int n)
{
    int i0 = (blockIdx.x * blockDim.x + threadIdx.x) * 4;
    if (i0 >= n) return;

    const float4 z4 = *reinterpret_cast<const float4*>(z + i0);
    const float4 s4 = *reinterpret_cast<const float4*>(S + i0);
    const float4 v4 = *reinterpret_cast<const float4*>(V + i0);
    const float4 g4 = *reinterpret_cast<const float4*>(dVdt + i0);

    // halo: z[i0-2], z[i0-1] (8B-aligned since i0 % 4 == 0), z[i0+4]
    float zm2 = 0.0f, zm1 = 0.0f;
    if (i0 >= 2) {
        const float2 t2 = *reinterpret_cast<const float2*>(z + i0 - 2);
        zm2 = t2.x; zm1 = t2.y;
    }
    float zp4 = (i0 + 4 < n) ? z[i0 + 4] : 0.0f;

    // lz[j] = z[i0-2+j], ld[j] = z[i0-1+j] - z[i0-2+j]
    float lz[7] = {zm2, zm1, z4.x, z4.y, z4.z, z4.w, zp4};
    float ld[6];
#pragma unroll
    for (int j = 0; j < 6; ++j) ld[j] = lz[j + 1] - lz[j];

    const float sv[4] = {s4.x, s4.y, s4.z, s4.w};
    float dz[4];
#pragma unroll
    for (int t = 0; t < 4; ++t) {
        const int i   = i0 + t;
        const float d0  = ld[t + 2];   // z[i+1]-z[i]
        const float dm1 = ld[t + 1];   // z[i]  -z[i-1]
        const float dm2 = ld[t];       // z[i-1]-z[i-2]
        const float wi   = limiter_f(d0, dm1);
        const float wim1 = limiter_f(dm1, dm2);
        // interior (i >= 2, i <= n-2):
        float val = -2.0f * (dm1 + 0.4f * (wi - wim1)) - sv[t];
        if (i == 1)     val = -2.0f * (dm1 + 0.4f * wi) - sv[t];          // wi_1[0] = 0
        if (i == 0)     val = -2.0f * lz[2] - sv[t];                      // -z[0]/DTS - S[0]
        if (i == n - 1) val = 2.0f * (lz[t + 1] + 0.4f * wim1) - sv[t];   // z[n-2] + coef*wi[-1]
        dz[t] = val;
    }

    *reinterpret_cast<float4*>(out + i0) = make_float4(dz[0], dz[1], dz[2], dz[3]);

    float4 h4;
    h4.x = h_func(v4.x, g4.x);
    h4.y = h_func(v4.y, g4.y);
    h4.z = h_func(v4.z, g4.z);
    h4.w = h_func(v4.w, g4.w);
    *reinterpret_cast<float4*>(out + n + i0) = h4;
}

extern "C" void kernel_launch(void* const* d_in, const int* in_sizes, int n_in,
                              void* d_out, int out_size, void* d_ws, size_t ws_size,
                              hipStream_t stream) {
    const float* z    = (const float*)d_in[0];
    const float* S    = (const float*)d_in[1];
    const float* V    = (const float*)d_in[2];
    const float* dVdt = (const float*)d_in[3];
    float* out = (float*)d_out;
    const int n = in_sizes[0];

    const int threads = 256;
    const int blocks = (n / 4 + threads - 1) / threads;
    neuron_kernel<<<blocks, threads, 0, stream>>>(z, S, V, dVdt, out, n);
}